// Round 3
// baseline (158.067 us; speedup 1.0000x reference)
//
#include <hip/hip_runtime.h>
#include <hip/hip_bf16.h>

// GQA prefill: B=2 T=2048 DM=768 H=12 HKV=4 DH=64 WIN=512 GLB=64
// 5 launches: prep(convert+rope) | transpose-all | fused QKV GEMM (rope fused,
// V transposed) | flash attn (KV-split wave pairs, K-prefetch dbuf, defer-max)
// | out GEMM.

typedef __attribute__((ext_vector_type(8))) short bf16x8;
typedef __attribute__((ext_vector_type(4))) float f32x4;
typedef __attribute__((ext_vector_type(4))) unsigned short u16x4;

#define MFMA __builtin_amdgcn_mfma_f32_16x16x32_bf16

constexpr int BB = 2, TT = 2048, DM = 768, HH = 12, HKV = 4, DH = 64;
constexpr int WIN = 512, GLB = 64;
constexpr float SC2 = 0.18033688011112042f; // 0.125 * log2(e)

__device__ __forceinline__ unsigned short f2b(float f) {
    union { float f; unsigned int u; } v; v.f = f;
    unsigned int r = v.u + 0x7fffu + ((v.u >> 16) & 1u);
    return (unsigned short)(r >> 16);
}

// ---------- prep: x -> bf16 (blocks 0..3071), rope table (blocks 3072..3327)
__global__ __launch_bounds__(256) void k_prep(const float* __restrict__ x,
                                              unsigned short* __restrict__ xb,
                                              float2* __restrict__ rope) {
    int bid = blockIdx.x, tid = threadIdx.x;
    if (bid < 3072) {
        int i = bid * 256 + tid;
        float4 v = ((const float4*)x)[i];
        u16x4 o; o.x = f2b(v.x); o.y = f2b(v.y); o.z = f2b(v.z); o.w = f2b(v.w);
        ((u16x4*)xb)[i] = o;
    } else {
        int i = (bid - 3072) * 256 + tid;  // T*32
        int t = i >> 5, p = i & 31;
        float inv = exp2f(-(float)p * (13.287712379549449f / 32.0f)); // 10000^(-p/32)
        float ang = (float)t * inv;
        rope[i] = make_float2(cosf(ang), sinf(ang));
    }
}

// ---------- transpose all weights: f32 [K][N] -> bf16 [N][K], LDS 32x32 tiles
__global__ __launch_bounds__(256) void k_tw(const float* __restrict__ wq,
                                            const float* __restrict__ wk,
                                            const float* __restrict__ wv,
                                            const float* __restrict__ wo,
                                            unsigned short* __restrict__ wqT,
                                            unsigned short* __restrict__ wkT,
                                            unsigned short* __restrict__ wvT,
                                            unsigned short* __restrict__ woT) {
    __shared__ float t[32][33];
    int bid = blockIdx.x;
    const float* src; unsigned short* dst; int N, tile;
    if (bid < 576)      { src = wq; dst = wqT; N = 768; tile = bid; }
    else if (bid < 768) { src = wk; dst = wkT; N = 256; tile = bid - 576; }
    else if (bid < 960) { src = wv; dst = wvT; N = 256; tile = bid - 768; }
    else                { src = wo; dst = woT; N = 768; tile = bid - 960; }
    int ntiles = N / 32;
    int k0 = (tile / ntiles) * 32, n0 = (tile % ntiles) * 32;
    int tx = threadIdx.x & 31, ty = threadIdx.x >> 5;
    #pragma unroll
    for (int e = 0; e < 4; ++e) {
        int r = ty + e * 8;
        t[r][tx] = src[(size_t)(k0 + r) * N + n0 + tx];
    }
    __syncthreads();
    #pragma unroll
    for (int e = 0; e < 4; ++e) {
        int r = ty + e * 8;
        dst[(size_t)(n0 + r) * DM + k0 + tx] = f2b(t[tx][r]);
    }
}

// ---------- fused QKV projection GEMM: y<12 Q(rope), y<16 K(rope), else V(transposed)
__global__ __launch_bounds__(256) void k_qkv(const unsigned short* __restrict__ xb,
                                             const unsigned short* __restrict__ wqT,
                                             const unsigned short* __restrict__ wkT,
                                             const unsigned short* __restrict__ wvT,
                                             unsigned short* __restrict__ qb,
                                             unsigned short* __restrict__ kb,
                                             unsigned short* __restrict__ vtb,
                                             const float2* __restrict__ rope) {
    const int wave = threadIdx.x >> 6, lane = threadIdx.x & 63;
    const int quad = lane >> 4, col = lane & 15;
    const int y = blockIdx.y;
    const int m0 = blockIdx.x * 128 + wave * 32;
    int mode, hl;
    const unsigned short* Bt;
    if (y < 12)      { mode = 0; hl = y;      Bt = wqT + (size_t)hl * 64 * DM; }
    else if (y < 16) { mode = 1; hl = y - 12; Bt = wkT + (size_t)hl * 64 * DM; }
    else             { mode = 2; hl = y - 16; Bt = wvT + (size_t)hl * 64 * DM; }

    const unsigned short* ap = xb + (size_t)(m0 + col) * DM + quad * 8;
    const unsigned short* bp = Bt + (size_t)col * DM + quad * 8;

    f32x4 acc[2][4];
    #pragma unroll
    for (int rt = 0; rt < 2; ++rt)
        #pragma unroll
        for (int nt = 0; nt < 4; ++nt) acc[rt][nt] = f32x4{0.f, 0.f, 0.f, 0.f};

    #pragma unroll 4
    for (int k = 0; k < DM; k += 32) {
        bf16x8 a0 = *(const bf16x8*)(ap + k);
        bf16x8 a1 = *(const bf16x8*)(ap + 16 * DM + k);
        #pragma unroll
        for (int nt = 0; nt < 4; ++nt) {
            bf16x8 b = *(const bf16x8*)(bp + (size_t)nt * 16 * DM + k);
            acc[0][nt] = MFMA(a0, b, acc[0][nt], 0, 0, 0);
            acc[1][nt] = MFMA(a1, b, acc[1][nt], 0, 0, 0);
        }
    }

    if (mode == 2) {
        int b = m0 >> 11;
        #pragma unroll
        for (int nt = 0; nt < 4; ++nt)
            #pragma unroll
            for (int rt = 0; rt < 2; ++rt)
                #pragma unroll
                for (int r = 0; r < 4; ++r) {
                    int m = m0 + rt * 16 + quad * 4 + r;
                    int t = m & (TT - 1);
                    int d = nt * 16 + col;
                    vtb[((size_t)(b * HKV + hl) * DH + d) * TT + t] = f2b(acc[rt][nt][r]);
                }
        return;
    }
    int nheads = (mode == 0) ? HH : HKV;
    unsigned short* ob = (mode == 0) ? qb : kb;
    #pragma unroll
    for (int rt = 0; rt < 2; ++rt)
        #pragma unroll
        for (int r = 0; r < 4; ++r) {
            int m = m0 + rt * 16 + quad * 4 + r;
            int t = m & (TT - 1);
            int b = m >> 11;
            float2 cs0 = rope[t * 32 + col];
            float2 cs1 = rope[t * 32 + 16 + col];
            float v0 = acc[rt][0][r], v1 = acc[rt][1][r], v2 = acc[rt][2][r], v3 = acc[rt][3][r];
            unsigned short* dst = ob + ((size_t)(b * nheads + hl) * TT + t) * DH + col;
            dst[0]  = f2b(v0 * cs0.x - v2 * cs0.y);
            dst[16] = f2b(v1 * cs1.x - v3 * cs1.y);
            dst[32] = f2b(v2 * cs0.x + v0 * cs0.y);
            dst[48] = f2b(v3 * cs1.x + v1 * cs1.y);
        }
}

// ---------- output projection GEMM (f32 out)
__global__ __launch_bounds__(256) void k_out(const unsigned short* __restrict__ ao,
                                             const unsigned short* __restrict__ woT,
                                             float* __restrict__ out) {
    const int wave = threadIdx.x >> 6, lane = threadIdx.x & 63;
    const int quad = lane >> 4, col = lane & 15;
    const int m0 = blockIdx.x * 128 + wave * 32;
    const int n0 = blockIdx.y * 64;

    const unsigned short* ap = ao + (size_t)(m0 + col) * DM + quad * 8;
    const unsigned short* bp = woT + (size_t)(n0 + col) * DM + quad * 8;

    f32x4 acc[2][4];
    #pragma unroll
    for (int rt = 0; rt < 2; ++rt)
        #pragma unroll
        for (int nt = 0; nt < 4; ++nt) acc[rt][nt] = f32x4{0.f, 0.f, 0.f, 0.f};

    #pragma unroll 4
    for (int k = 0; k < DM; k += 32) {
        bf16x8 a0 = *(const bf16x8*)(ap + k);
        bf16x8 a1 = *(const bf16x8*)(ap + 16 * DM + k);
        #pragma unroll
        for (int nt = 0; nt < 4; ++nt) {
            bf16x8 b = *(const bf16x8*)(bp + (size_t)nt * 16 * DM + k);
            acc[0][nt] = MFMA(a0, b, acc[0][nt], 0, 0, 0);
            acc[1][nt] = MFMA(a1, b, acc[1][nt], 0, 0, 0);
        }
    }
    #pragma unroll
    for (int rt = 0; rt < 2; ++rt)
        #pragma unroll
        for (int nt = 0; nt < 4; ++nt)
            #pragma unroll
            for (int r = 0; r < 4; ++r) {
                int m = m0 + rt * 16 + quad * 4 + r;
                out[(size_t)m * DM + n0 + nt * 16 + col] = acc[rt][nt][r];
            }
}

// ---------- flash attention: 1536 blocks, 4 waves; wave pair p covers 16 q-rows,
// halves split KV tile list odd/even; flash-merge at end via LDS.
__global__ __launch_bounds__(256) void k_attn(const unsigned short* __restrict__ Q,
                                              const unsigned short* __restrict__ K,
                                              const unsigned short* __restrict__ Vt,
                                              unsigned short* __restrict__ AO) {
    __shared__ float plds[4][16 * 68];   // per-wave P transpose; reused as merge O buf
    __shared__ float2 ml_sh[2][16];
    const int wave = threadIdx.x >> 6, lane = threadIdx.x & 63;
    const int quad = lane >> 4, col = lane & 15;
    const int pair = wave >> 1, half = wave & 1;
    // bijective XCD swizzle: 1536 = 8 XCDs x 192; each XCD gets 3 full KV panels
    const int lbid = (blockIdx.x & 7) * 192 + (blockIdx.x >> 3);
    const int qb = lbid & 63, bh = lbid >> 6;
    const int h = bh % HH, b = bh / HH;
    const int hkv = h / 3;
    const int i0 = qb * 32 + pair * 16;
    const int iq = i0 + quad * 4;

    const unsigned short* qbase = Q + ((size_t)(b * HH + h) * TT + i0 + col) * DH + quad * 8;
    const bf16x8 qf0 = *(const bf16x8*)qbase;
    const bf16x8 qf1 = *(const bf16x8*)(qbase + 32);
    const unsigned short* kbase = K + (size_t)(b * HKV + hkv) * TT * DH;
    const unsigned short* vbase = Vt + (size_t)(b * HKV + hkv) * DH * TT;

    float m_run[4] = {-1e30f, -1e30f, -1e30f, -1e30f};
    float l_lane[4] = {0.f, 0.f, 0.f, 0.f};
    f32x4 accO[4];
    #pragma unroll
    for (int dt = 0; dt < 4; ++dt) accO[dt] = f32x4{0.f, 0.f, 0.f, 0.f};
    float* pw = plds[wave];

    int jw0 = (i0 - WIN + 1) & ~63; if (jw0 < 64) jw0 = 64;
    const int jlast = (i0 + 15) & ~63;
    const int nt = 1 + ((jlast >= jw0) ? (((jlast - jw0) >> 6) + 1) : 0);

    auto j0_of = [&](int t) { return (t == 0) ? 0 : (jw0 + ((t - 1) << 6)); };
    auto loadK = [&](int j0, bf16x8 (&kf)[8]) {
        const unsigned short* kp = kbase + (size_t)(j0 + col) * DH + quad * 8;
        #pragma unroll
        for (int f = 0; f < 4; ++f) {
            kf[f]     = *(const bf16x8*)(kp + (size_t)(f * 16) * DH);
            kf[4 + f] = *(const bf16x8*)(kp + (size_t)(f * 16) * DH + 32);
        }
    };

    auto tile_body = [&](int t, bf16x8 (&kc)[8], bf16x8 (&kn)[8]) {
        const int j0 = j0_of(t);
        const int mode = (t == 0) ? ((i0 < 64) ? 1 : 0)
                       : (((j0 + 63 > i0) || (j0 <= i0 + 15 - WIN)) ? 2 : 0);
        // V loads for current tile issued early (consumed ~400cy later by PV)
        bf16x8 vf[8];
        const unsigned short* vp = vbase + (size_t)col * TT + j0 + quad * 8;
        #pragma unroll
        for (int dt = 0; dt < 4; ++dt) {
            vf[dt]     = *(const bf16x8*)(vp + (size_t)(dt * 16) * TT);
            vf[4 + dt] = *(const bf16x8*)(vp + (size_t)(dt * 16) * TT + 32);
        }
        f32x4 s[4];
        #pragma unroll
        for (int f = 0; f < 4; ++f) s[f] = f32x4{0.f, 0.f, 0.f, 0.f};
        __builtin_amdgcn_s_setprio(1);
        #pragma unroll
        for (int f = 0; f < 4; ++f) {
            s[f] = MFMA(qf0, kc[f], s[f], 0, 0, 0);
            s[f] = MFMA(qf1, kc[4 + f], s[f], 0, 0, 0);
        }
        __builtin_amdgcn_s_setprio(0);
        // prefetch K for this wave's next tile (t+2)
        if (t + 2 < nt) loadK(j0_of(t + 2), kn);

        const int d0 = iq - j0 - col; // (i - j) at r=0,f=0
        if (mode == 1) {
            #pragma unroll
            for (int f = 0; f < 4; ++f)
                #pragma unroll
                for (int r = 0; r < 4; ++r)
                    if (d0 + r - f * 16 < 0) s[f][r] = -3e30f;
        } else if (mode == 2) {
            #pragma unroll
            for (int f = 0; f < 4; ++f)
                #pragma unroll
                for (int r = 0; r < 4; ++r)
                    if ((unsigned)(d0 + r - f * 16) >= (unsigned)WIN) s[f][r] = -3e30f;
        }

        float mx[4] = {-3e30f, -3e30f, -3e30f, -3e30f};
        #pragma unroll
        for (int f = 0; f < 4; ++f)
            #pragma unroll
            for (int r = 0; r < 4; ++r) mx[r] = fmaxf(mx[r], s[f][r]);

        bool ok = (mx[0] <= m_run[0] + 44.f) && (mx[1] <= m_run[1] + 44.f) &&
                  (mx[2] <= m_run[2] + 44.f) && (mx[3] <= m_run[3] + 44.f);
        if (!__all(ok)) {
            #pragma unroll
            for (int r = 0; r < 4; ++r) {
                float t2 = mx[r];
                t2 = fmaxf(t2, __shfl_xor(t2, 1));
                t2 = fmaxf(t2, __shfl_xor(t2, 2));
                t2 = fmaxf(t2, __shfl_xor(t2, 4));
                t2 = fmaxf(t2, __shfl_xor(t2, 8));
                float mn = fmaxf(m_run[r], t2);
                float corr = exp2f((m_run[r] - mn) * SC2);
                m_run[r] = mn;
                l_lane[r] *= corr;
                #pragma unroll
                for (int dt = 0; dt < 4; ++dt) accO[dt][r] *= corr;
            }
        }

        #pragma unroll
        for (int r = 0; r < 4; ++r) {
            float base = m_run[r] * SC2;
            float ps = 0.f;
            #pragma unroll
            for (int f = 0; f < 4; ++f) {
                float p = exp2f(__builtin_fmaf(s[f][r], SC2, -base));
                pw[(quad * 4 + r) * 68 + f * 16 + col] = p;
                ps += p;
            }
            l_lane[r] += ps;
        }

        bf16x8 pa[2];
        #pragma unroll
        for (int ks = 0; ks < 2; ++ks) {
            float4 lo = *(const float4*)&pw[col * 68 + ks * 32 + quad * 8];
            float4 hi = *(const float4*)&pw[col * 68 + ks * 32 + quad * 8 + 4];
            union { bf16x8 v; unsigned int u[4]; } pk;
            asm("v_cvt_pk_bf16_f32 %0, %1, %2" : "=v"(pk.u[0]) : "v"(lo.x), "v"(lo.y));
            asm("v_cvt_pk_bf16_f32 %0, %1, %2" : "=v"(pk.u[1]) : "v"(lo.z), "v"(lo.w));
            asm("v_cvt_pk_bf16_f32 %0, %1, %2" : "=v"(pk.u[2]) : "v"(hi.x), "v"(hi.y));
            asm("v_cvt_pk_bf16_f32 %0, %1, %2" : "=v"(pk.u[3]) : "v"(hi.z), "v"(hi.w));
            pa[ks] = pk.v;
        }
        __builtin_amdgcn_s_setprio(1);
        #pragma unroll
        for (int dt = 0; dt < 4; ++dt) {
            accO[dt] = MFMA(pa[0], vf[dt], accO[dt], 0, 0, 0);
            accO[dt] = MFMA(pa[1], vf[4 + dt], accO[dt], 0, 0, 0);
        }
        __builtin_amdgcn_s_setprio(0);
    };

    if (half < nt) {
        int tcur = half;
        bf16x8 kA[8], kB[8];
        loadK(j0_of(tcur), kA);
        while (true) {
            tile_body(tcur, kA, kB); tcur += 2;
            if (tcur >= nt) break;
            tile_body(tcur, kB, kA); tcur += 2;
            if (tcur >= nt) break;
        }
    }

    float l_red[4];
    #pragma unroll
    for (int r = 0; r < 4; ++r) {
        float lt = l_lane[r];
        lt += __shfl_xor(lt, 1); lt += __shfl_xor(lt, 2);
        lt += __shfl_xor(lt, 4); lt += __shfl_xor(lt, 8);
        l_red[r] = lt;
    }

    __syncthreads();                       // all waves done with P buffers
    float* osh = &plds[0][0];              // reuse as [2][64][21] f32
    const int oidx = (pair * 64 + lane) * 21;
    if (half == 1) {
        #pragma unroll
        for (int dt = 0; dt < 4; ++dt)
            #pragma unroll
            for (int r = 0; r < 4; ++r)
                osh[oidx + dt * 4 + r] = accO[dt][r];
        if (col == 0) {
            #pragma unroll
            for (int r = 0; r < 4; ++r)
                ml_sh[pair][quad * 4 + r] = make_float2(m_run[r], l_red[r]);
        }
    }
    __syncthreads();
    if (half == 0) {
        float gA[4], gB[4];
        #pragma unroll
        for (int r = 0; r < 4; ++r) {
            float2 mlB = ml_sh[pair][quad * 4 + r];
            float mM = fmaxf(m_run[r], mlB.x);
            float fA = exp2f((m_run[r] - mM) * SC2);
            float fB = exp2f((mlB.x - mM) * SC2);
            float inv = 1.0f / (l_red[r] * fA + mlB.y * fB);
            gA[r] = fA * inv; gB[r] = fB * inv;
        }
        #pragma unroll
        for (int dt = 0; dt < 4; ++dt)
            #pragma unroll
            for (int r = 0; r < 4; ++r) {
                float o = accO[dt][r] * gA[r] + osh[oidx + dt * 4 + r] * gB[r];
                int t = i0 + quad * 4 + r;
                AO[((size_t)b * TT + t) * DM + h * DH + dt * 16 + col] = f2b(o);
            }
    }
}

extern "C" void kernel_launch(void* const* d_in, const int* in_sizes, int n_in,
                              void* d_out, int out_size, void* d_ws, size_t ws_size,
                              hipStream_t stream) {
    const float* x  = (const float*)d_in[0];
    const float* wq = (const float*)d_in[1];
    const float* wk = (const float*)d_in[2];
    const float* wv = (const float*)d_in[3];
    const float* wo = (const float*)d_in[4];
    float* out = (float*)d_out;

    char* ws = (char*)d_ws;
    size_t off = 0;
    auto alloc = [&](size_t bytes) -> void* {
        void* p = ws + off;
        off += (bytes + 255) & ~(size_t)255;
        return p;
    };
    const int M = BB * TT; // 4096
    unsigned short* xb  = (unsigned short*)alloc((size_t)M * DM * 2);
    unsigned short* wqT = (unsigned short*)alloc((size_t)DM * DM * 2);
    unsigned short* wkT = (unsigned short*)alloc((size_t)(HKV * DH) * DM * 2);
    unsigned short* wvT = (unsigned short*)alloc((size_t)(HKV * DH) * DM * 2);
    unsigned short* woT = (unsigned short*)alloc((size_t)DM * DM * 2);
    unsigned short* qb  = (unsigned short*)alloc((size_t)BB * HH * TT * DH * 2);
    unsigned short* kb  = (unsigned short*)alloc((size_t)BB * HKV * TT * DH * 2);
    unsigned short* vtb = (unsigned short*)alloc((size_t)BB * HKV * DH * TT * 2);
    unsigned short* ao  = (unsigned short*)alloc((size_t)M * DM * 2);
    float2* rope        = (float2*)alloc((size_t)TT * 32 * sizeof(float2));

    k_prep<<<3328, 256, 0, stream>>>(x, xb, rope);
    k_tw<<<1536, 256, 0, stream>>>(wq, wk, wv, wo, wqT, wkT, wvT, woT);
    k_qkv<<<dim3(M / 128, 20), 256, 0, stream>>>(xb, wqT, wkT, wvT, qb, kb, vtb, rope);
    k_attn<<<1536, 256, 0, stream>>>(qb, kb, vtb, ao);
    k_out<<<dim3(M / 128, 12), 256, 0, stream>>>(ao, woT, out);
}